// Round 6
// baseline (257.837 us; speedup 1.0000x reference)
//
#include <hip/hip_runtime.h>

// B=4, S=1024, H=16, D=64 attention, clipped softmax.
// Round 14: occupancy 2->4 waves/SIMD. r13 proved split-K correct but occupancy
// stayed 19% (2 blocks/CU co-resident): same 66us as r10. Theory: unified
// reg usage (112 arch + ~32 acc > 128) and/or launch_bounds(256,2)'s
// waves-per-eu=2 pin HW at 2 waves/SIMD. Fixes (one goal, both mechanisms):
//  1) SINGLE staging reg buffer (drop krB/vrB, -40 VGPR). Pipeline per step:
//     WRITE(chunk i+1 from R); ISSUE(chunk i+2 -> R); BAR; COMPUTE(chunk i).
//     Loads have ~1 step + barrier of slack; ring-of-4 reuse stays
//     barrier-protected (reader is >=2 BARs before slot rewrite).
//  2) explicit __attribute__((amdgpu_flat_work_group_size(256,256),
//     amdgpu_waves_per_eu(4))): allocator must fit >=4 waves/EU (<=128
//     unified regs, which the slimmed body fits), scheduler unconstrained.
// Everything else (staging maps, swizzles, step32v, epilogue, combine) is
// r13-verbatim (PASSED, absmax 0.0022).
// LDS image per 32-key chunk slot (r9/r10-proven):
//   K: [frag 0..3][swz1k(n16*64 + quad*16)]       (4 x 1KB)
//   V: 4096 + [dt 0..3][swz1k(o*256 + n16v*16)]   (4 x 1KB)
#define SS 1024
#define HH 16
#define DD 64

typedef short bf16x8 __attribute__((ext_vector_type(8)));
typedef float f32x4 __attribute__((ext_vector_type(4)));

__device__ __forceinline__ unsigned pk2(float a, float b) {   // pack 2 bf16
    unsigned ua = __float_as_uint(a) + 0x8000u;
    unsigned ub = __float_as_uint(b) + 0x8000u;
    return (ub & 0xffff0000u) | (ua >> 16);
}
__device__ __forceinline__ unsigned short f2bf(float a) {
    return (unsigned short)((__float_as_uint(a) + 0x8000u) >> 16);
}
__device__ __forceinline__ f32x4 mfma16(bf16x8 a, bf16x8 b, f32x4 c) {
    return __builtin_amdgcn_mfma_f32_16x16x32_bf16(a, b, c, 0, 0, 0);
}
// sigma within 32-key chunks (verified r4/r5): pos x holds key ((q^(b>>1))<<3)|(a<<2)|b
__device__ __forceinline__ int sig5(int x) {
    int a = (x >> 4) & 1, qs = (x >> 2) & 3, b2 = x & 3;
    return ((qs ^ (b2 >> 1)) << 3) | (a << 2) | b2;
}
// bank-conflict swizzle within a 1KB fragment (r9-proven): XOR bits 7..9 into 4..6
__device__ __forceinline__ unsigned swz1k(unsigned o) {
    return o ^ (((o >> 7) & 7u) << 4);
}

// compute one 32-key step: QK^T -> exp -> PV (all in registers) [r8..r13-proven]
__device__ __forceinline__ void step32v(bf16x8 K0, bf16x8 K1, bf16x8 K2, bf16x8 K3,
                                        bf16x8 V0, bf16x8 V1, bf16x8 V2, bf16x8 V3,
                                        const bf16x8 qf[2][2],
                                        f32x4 oacc[2][4], float su[2]) {
    const f32x4 zero = {0.f, 0.f, 0.f, 0.f};
    const float LOG2E = 1.44269504f;
    f32x4 S[2][2];
    S[0][0] = mfma16(K1, qf[0][1], mfma16(K0, qf[0][0], zero));
    S[1][0] = mfma16(K1, qf[1][1], mfma16(K0, qf[1][0], zero));
    S[0][1] = mfma16(K3, qf[0][1], mfma16(K2, qf[0][0], zero));
    S[1][1] = mfma16(K3, qf[1][1], mfma16(K2, qf[1][0], zero));
    #pragma unroll
    for (int s = 0; s < 2; ++s) {
        unsigned P0[2], P1[2];
        #pragma unroll
        for (int ct = 0; ct < 2; ++ct) {
            float e0 = __builtin_amdgcn_exp2f(S[s][ct][0] * LOG2E);
            float e1 = __builtin_amdgcn_exp2f(S[s][ct][1] * LOG2E);
            float e2 = __builtin_amdgcn_exp2f(S[s][ct][2] * LOG2E);
            float e3 = __builtin_amdgcn_exp2f(S[s][ct][3] * LOG2E);
            su[s] += (e0 + e1) + (e2 + e3);
            P0[ct] = pk2(e0, e1);
            P1[ct] = pk2(e2, e3);
        }
        union { uint4 u; bf16x8 f; } pf;
        pf.u.x = P0[0];
        pf.u.y = (unsigned)__shfl_xor((int)P1[0], 16);
        pf.u.z = P0[1];
        pf.u.w = (unsigned)__shfl_xor((int)P1[1], 16);
        #pragma unroll
        for (int dt = 0; dt < 4; ++dt) {
            bf16x8 vv = dt == 0 ? V0 : dt == 1 ? V1 : dt == 2 ? V2 : V3;
            oacc[s][dt] = mfma16(vv, pf.f, oacc[s][dt]);
        }
    }
}

// ---------------- split-K partial attention (single staging buffer) ----------------
__global__ __attribute__((amdgpu_flat_work_group_size(256, 256), amdgpu_waves_per_eu(4)))
void attn_partial(const float* __restrict__ q, const float* __restrict__ k,
                  const float* __restrict__ v, float* __restrict__ wso,
                  float* __restrict__ wss) {
    // 4-slot ring, 8KB/slot: [0,4K) = K frags (4x1KB), [4K,8K) = V frags
    __shared__ __align__(16) unsigned short ldsbuf[16384];   // 32 KB

    const int t = threadIdx.x, lane = t & 63, w = t >> 6;
    const int n16 = lane & 15, quad = lane >> 4;
    const int bx = blockIdx.x;                // 1024 blocks
    const int bh = bx & 63, rest = bx >> 6;   // same bh -> same XCD (bx%8==bh%8)
    const int qt = rest >> 1, half = rest & 1;
    const int h = bh & 15, b = bh >> 4;
    const int qbase = qt * 128 + w * 32;
    const int cbase = half * 16;              // this block's 16 key-chunks

    // ---- staging task decomposition (r10/r13 verbatim) ----
    // K: all 256 threads; thread = (kx 0..31, khalf, ku 0..3), 2 float4 reads,
    //    1 swizzled ds_write_b128
    const int kx = t >> 3, khalf = (t >> 2) & 1, ku = t & 3;
    const int kf = ((kx >> 4) & 1) * 2 + khalf;
    const unsigned kwoff = (unsigned)(kf * 1024)
                         + swz1k((unsigned)((kx & 15) * 64 + ku * 16));
    const int ksig = sig5(kx);
    // V: every 4th thread; vtid = t>>2 = (vo 0..3, vvc 0..15),
    //    8 float4 reads (keys vo*8..+8 at d-group vvc), 4 swizzled ds_write_b128
    const bool vact = (t & 3) == 0;
    const int vtid = t >> 2, vo = vtid >> 4, vvc = vtid & 15;

    const float4* kbase = (const float4*)k + ((size_t)(b * SS) * HH + h) * 16
                        + khalf * 8 + 2 * ku;
    const float4* vbase = (const float4*)v + ((size_t)(b * SS + vo * 8) * HH + h) * 16
                        + vvc;

    // Q B-frags: q = sub*16+n16, d = ks*32+quad*8+j, pre-scaled 1/8
    bf16x8 qf[2][2];
    #pragma unroll
    for (int s = 0; s < 2; ++s)
      #pragma unroll
      for (int ks = 0; ks < 2; ++ks) {
        const float* p = q + (((size_t)(b * SS + qbase + s * 16 + n16) * HH + h) * DD)
                           + ks * 32 + quad * 8;
        float4 x = ((const float4*)p)[0];
        float4 y = ((const float4*)p)[1];
        bf16x8 f;
        f[0] = (short)f2bf(x.x * 0.125f); f[1] = (short)f2bf(x.y * 0.125f);
        f[2] = (short)f2bf(x.z * 0.125f); f[3] = (short)f2bf(x.w * 0.125f);
        f[4] = (short)f2bf(y.x * 0.125f); f[5] = (short)f2bf(y.y * 0.125f);
        f[6] = (short)f2bf(y.z * 0.125f); f[7] = (short)f2bf(y.w * 0.125f);
        qf[s][ks] = f;
      }

    f32x4 oacc[2][4];    // O^T: row d = dt*16+quad*4+r, col q = sub*16+n16
    #pragma unroll
    for (int s = 0; s < 2; ++s)
      #pragma unroll
      for (int dt = 0; dt < 4; ++dt) oacc[s][dt] = f32x4{0.f, 0.f, 0.f, 0.f};
    float su[2] = {0.f, 0.f};

    // per-lane swizzled read offsets inside a slot (r9/r10-identical)
    const unsigned okK = swz1k(((unsigned)n16 << 6) | ((unsigned)quad << 4));
    const unsigned okV = swz1k(((unsigned)quad << 8) | ((unsigned)n16 << 4));

#define ISSUE(ci, kr, vr) do {                                                   \
    const int c_ = cbase + (ci);                                                 \
    const float4* ks_ = kbase + (size_t)(c_ * 32 + ksig) * 256;                  \
    kr[0] = ks_[0]; kr[1] = ks_[1];                                              \
    if (vact) {                                                                  \
        const float4* vs_ = vbase + (size_t)c_ * 8192;                           \
        _Pragma("unroll")                                                        \
        for (int kk_ = 0; kk_ < 8; ++kk_) vr[kk_] = vs_[kk_ * 256];              \
    }                                                                            \
} while (0)

#define WRITE(slot, kr, vr) do {                                                 \
    char* sb_ = (char*)ldsbuf + (slot) * 8192;                                   \
    uint4 kv_;                                                                   \
    kv_.x = pk2(kr[0].x, kr[0].y); kv_.y = pk2(kr[0].z, kr[0].w);                \
    kv_.z = pk2(kr[1].x, kr[1].y); kv_.w = pk2(kr[1].z, kr[1].w);                \
    *(uint4*)(sb_ + kwoff) = kv_;                                                \
    if (vact) {                                                                  \
        const float* fr_ = (const float*)vr;                                     \
        _Pragma("unroll")                                                        \
        for (int cc_ = 0; cc_ < 4; ++cc_) {                                      \
            const int d_ = 4 * vvc + cc_;                                        \
            uint4 q4_;                                                           \
            q4_.x = pk2(fr_[0*4+cc_], fr_[1*4+cc_]);                             \
            q4_.y = pk2(fr_[2*4+cc_], fr_[3*4+cc_]);                             \
            q4_.z = pk2(fr_[4*4+cc_], fr_[5*4+cc_]);                             \
            q4_.w = pk2(fr_[6*4+cc_], fr_[7*4+cc_]);                             \
            *(uint4*)(sb_ + 4096 + (d_ >> 4) * 1024 +                            \
                      swz1k((unsigned)(vo * 256 + (d_ & 15) * 16))) = q4_;       \
        }                                                                        \
    }                                                                            \
} while (0)

// raw barrier: drain LDS writes, NEVER vmcnt (keeps global prefetch in flight)
#define BAR asm volatile("s_waitcnt lgkmcnt(0)\n\ts_barrier" ::: "memory")

#define COMPUTE(slot) do {                                                       \
    const char* cb_ = (const char*)ldsbuf + (slot) * 8192;                       \
    bf16x8 K0 = *(const bf16x8*)(cb_ + okK);                                     \
    bf16x8 K1 = *(const bf16x8*)(cb_ + okK + 1024);                              \
    bf16x8 K2 = *(const bf16x8*)(cb_ + okK + 2048);                              \
    bf16x8 K3 = *(const bf16x8*)(cb_ + okK + 3072);                              \
    bf16x8 V0 = *(const bf16x8*)(cb_ + okV + 4096);                              \
    bf16x8 V1 = *(const bf16x8*)(cb_ + okV + 5120);                              \
    bf16x8 V2 = *(const bf16x8*)(cb_ + okV + 6144);                              \
    bf16x8 V3 = *(const bf16x8*)(cb_ + okV + 7168);                              \
    step32v(K0, K1, K2, K3, V0, V1, V2, V3, qf, oacc, su);                       \
} while (0)

    float4 kr[2], vr[8];

    // prologue: chunk0 -> slot0 (vmcnt auto at first use); chunk1 in flight
    ISSUE(0, kr, vr);
    WRITE(0, kr, vr);
    ISSUE(1, kr, vr);
    BAR;

    // steady state, one chunk per iteration:
    //   WRITE(chunk it+1 from R); ISSUE(chunk it+2 -> R); BAR; COMPUTE(chunk it)
    #pragma unroll 1
    for (int it = 0; it < 16; ++it) {
        WRITE((it + 1) & 3, kr, vr);                       // it=15: dead dup write
        { const int ci = (it + 2 < 16) ? it + 2 : 15; ISSUE(ci, kr, vr); }
        BAR;
        COMPUTE(it & 3);
    }
#undef ISSUE
#undef WRITE
#undef BAR
#undef COMPUTE

    // epilogue: reduce su across quads, store RAW partials (no normalize)
    #pragma unroll
    for (int s = 0; s < 2; ++s) {
        su[s] += __shfl_xor(su[s], 16);
        su[s] += __shfl_xor(su[s], 32);
    }
    const int pb = bh * 8 + qt;                       // 0..511
    float4* wo4 = (float4*)wso + (size_t)half * 1048576u;
    #pragma unroll
    for (int s = 0; s < 2; ++s)
      #pragma unroll
      for (int dt = 0; dt < 4; ++dt) {
        float4 val;
        val.x = oacc[s][dt][0]; val.y = oacc[s][dt][1];
        val.z = oacc[s][dt][2]; val.w = oacc[s][dt][3];
        wo4[((size_t)pb * 128 + w * 32 + s * 16 + n16) * 16 + dt * 4 + quad] = val;
      }
    if (quad == 0) {
        wss[half * 65536 + pb * 128 + w * 32 + n16]      = su[0];
        wss[half * 65536 + pb * 128 + w * 32 + 16 + n16] = su[1];
    }
}

// ---------------- combine: out = (oA+oB) / (suA+suB) ----------------
__global__ __launch_bounds__(256)
void combine_kernel(const float* __restrict__ wso, const float* __restrict__ wss,
                    float* __restrict__ out) {
    const unsigned gi = blockIdx.x * 256u + threadIdx.x;   // 0..1048575 float4s
    const unsigned row = gi >> 4, d4 = gi & 15;            // row 0..65535
    const float4* o4 = (const float4*)wso;
    float4 a = o4[gi];
    float4 c = o4[gi + 1048576u];
    float sc = 1.0f / (wss[row] + wss[row + 65536]);       // clamps inactive
    const unsigned pb = row >> 7, r128 = row & 127;
    const unsigned bh = pb >> 3, qt = pb & 7;
    const unsigned b = bh >> 4, h = bh & 15;
    float4 val;
    val.x = (a.x + c.x) * sc; val.y = (a.y + c.y) * sc;
    val.z = (a.z + c.z) * sc; val.w = (a.w + c.w) * sc;
    ((float4*)out)[(((size_t)b * SS + qt * 128 + r128) * HH + h) * 16 + d4] = val;
}

extern "C" void kernel_launch(void* const* d_in, const int* in_sizes, int n_in,
                              void* d_out, int out_size, void* d_ws, size_t ws_size,
                              hipStream_t stream) {
    const float* q = (const float*)d_in[0];
    const float* k = (const float*)d_in[1];
    const float* v = (const float*)d_in[2];
    float* o = (float*)d_out;
    float* wso = (float*)d_ws;                 // 2 x 65536 rows x 64 d = 32 MB
    float* wss = wso + 8388608;                // 2 x 65536 su = 0.5 MB
    hipLaunchKernelGGL(attn_partial, dim3(1024), dim3(256), 0, stream, q, k, v, wso, wss);
    hipLaunchKernelGGL(combine_kernel, dim3(4096), dim3(256), 0, stream, wso, wss, o);
}

// Round 7
// 136.770 us; speedup vs baseline: 1.8852x; 1.8852x over previous
//
#include <hip/hip_runtime.h>

// B=4, S=1024, H=16, D=64 attention, clipped softmax.
// Round 15: SUPERSTEP restructure (2 chunks per barrier). Facts so far:
//  - r8/r9/r10/r13: every structure = ~5000 cyc/step/wave (attn 65-72us),
//    across 8x different global-traffic volumes -> stall-bound, not BW/VALU.
//  - Occupancy pinned at 2 waves/SIMD (unified regs ~144 > 128); forcing 4
//    waves/EU (r12 launch_bounds, r14 waves_per_eu) caps arch VGPR at 64 ->
//    catastrophic scratch spill (190-370us). TLP axis is closed.
//  -> Raise ILP instead: one barrier per TWO chunks, two independent step
//     bodies (16 ds_read / 24 MFMA / 32 exp) after each BAR for the
//     scheduler to interleave. Staging regs already exist (r13's A/B sets).
// Hazard audit: slot s written at superstep j was last read at superstep
// j-2; BAR(j-1) lies between and its lgkmcnt(0) drains those reads -> safe.
// All addressing/packing/compute bytes = r13-verbatim (PASSED, absmax 0.0022).
// LDS image per 32-key chunk slot (r9/r10-proven):
//   K: [frag 0..3][swz1k(n16*64 + quad*16)]       (4 x 1KB)
//   V: 4096 + [dt 0..3][swz1k(o*256 + n16v*16)]   (4 x 1KB)
#define SS 1024
#define HH 16
#define DD 64

typedef short bf16x8 __attribute__((ext_vector_type(8)));
typedef float f32x4 __attribute__((ext_vector_type(4)));

__device__ __forceinline__ unsigned pk2(float a, float b) {   // pack 2 bf16
    unsigned ua = __float_as_uint(a) + 0x8000u;
    unsigned ub = __float_as_uint(b) + 0x8000u;
    return (ub & 0xffff0000u) | (ua >> 16);
}
__device__ __forceinline__ unsigned short f2bf(float a) {
    return (unsigned short)((__float_as_uint(a) + 0x8000u) >> 16);
}
__device__ __forceinline__ f32x4 mfma16(bf16x8 a, bf16x8 b, f32x4 c) {
    return __builtin_amdgcn_mfma_f32_16x16x32_bf16(a, b, c, 0, 0, 0);
}
// sigma within 32-key chunks (verified r4/r5): pos x holds key ((q^(b>>1))<<3)|(a<<2)|b
__device__ __forceinline__ int sig5(int x) {
    int a = (x >> 4) & 1, qs = (x >> 2) & 3, b2 = x & 3;
    return ((qs ^ (b2 >> 1)) << 3) | (a << 2) | b2;
}
// bank-conflict swizzle within a 1KB fragment (r9-proven): XOR bits 7..9 into 4..6
__device__ __forceinline__ unsigned swz1k(unsigned o) {
    return o ^ (((o >> 7) & 7u) << 4);
}

// compute one 32-key step: QK^T -> exp -> PV (all in registers) [r8..r13-proven]
__device__ __forceinline__ void step32v(bf16x8 K0, bf16x8 K1, bf16x8 K2, bf16x8 K3,
                                        bf16x8 V0, bf16x8 V1, bf16x8 V2, bf16x8 V3,
                                        const bf16x8 qf[2][2],
                                        f32x4 oacc[2][4], float su[2]) {
    const f32x4 zero = {0.f, 0.f, 0.f, 0.f};
    const float LOG2E = 1.44269504f;
    f32x4 S[2][2];
    S[0][0] = mfma16(K1, qf[0][1], mfma16(K0, qf[0][0], zero));
    S[1][0] = mfma16(K1, qf[1][1], mfma16(K0, qf[1][0], zero));
    S[0][1] = mfma16(K3, qf[0][1], mfma16(K2, qf[0][0], zero));
    S[1][1] = mfma16(K3, qf[1][1], mfma16(K2, qf[1][0], zero));
    #pragma unroll
    for (int s = 0; s < 2; ++s) {
        unsigned P0[2], P1[2];
        #pragma unroll
        for (int ct = 0; ct < 2; ++ct) {
            float e0 = __builtin_amdgcn_exp2f(S[s][ct][0] * LOG2E);
            float e1 = __builtin_amdgcn_exp2f(S[s][ct][1] * LOG2E);
            float e2 = __builtin_amdgcn_exp2f(S[s][ct][2] * LOG2E);
            float e3 = __builtin_amdgcn_exp2f(S[s][ct][3] * LOG2E);
            su[s] += (e0 + e1) + (e2 + e3);
            P0[ct] = pk2(e0, e1);
            P1[ct] = pk2(e2, e3);
        }
        union { uint4 u; bf16x8 f; } pf;
        pf.u.x = P0[0];
        pf.u.y = (unsigned)__shfl_xor((int)P1[0], 16);
        pf.u.z = P0[1];
        pf.u.w = (unsigned)__shfl_xor((int)P1[1], 16);
        #pragma unroll
        for (int dt = 0; dt < 4; ++dt) {
            bf16x8 vv = dt == 0 ? V0 : dt == 1 ? V1 : dt == 2 ? V2 : V3;
            oacc[s][dt] = mfma16(vv, pf.f, oacc[s][dt]);
        }
    }
}

// ---------------- split-K partial attention (superstep: 2 chunks / barrier) ----------------
__global__ __launch_bounds__(256, 2)
void attn_partial(const float* __restrict__ q, const float* __restrict__ k,
                  const float* __restrict__ v, float* __restrict__ wso,
                  float* __restrict__ wss) {
    // 4-slot ring, 8KB/slot: [0,4K) = K frags (4x1KB), [4K,8K) = V frags
    __shared__ __align__(16) unsigned short ldsbuf[16384];   // 32 KB

    const int t = threadIdx.x, lane = t & 63, w = t >> 6;
    const int n16 = lane & 15, quad = lane >> 4;
    const int bx = blockIdx.x;                // 1024 blocks
    const int bh = bx & 63, rest = bx >> 6;   // same bh -> same XCD (bx%8==bh%8)
    const int qt = rest >> 1, half = rest & 1;
    const int h = bh & 15, b = bh >> 4;
    const int qbase = qt * 128 + w * 32;
    const int cbase = half * 16;              // this block's 16 key-chunks

    // ---- staging task decomposition (r10/r13 verbatim) ----
    // K: all 256 threads; thread = (kx 0..31, khalf, ku 0..3), 2 float4 reads,
    //    1 swizzled ds_write_b128
    const int kx = t >> 3, khalf = (t >> 2) & 1, ku = t & 3;
    const int kf = ((kx >> 4) & 1) * 2 + khalf;
    const unsigned kwoff = (unsigned)(kf * 1024)
                         + swz1k((unsigned)((kx & 15) * 64 + ku * 16));
    const int ksig = sig5(kx);
    // V: every 4th thread; vtid = t>>2 = (vo 0..3, vvc 0..15),
    //    8 float4 reads (keys vo*8..+8 at d-group vvc), 4 swizzled ds_write_b128
    const bool vact = (t & 3) == 0;
    const int vtid = t >> 2, vo = vtid >> 4, vvc = vtid & 15;

    const float4* kbase = (const float4*)k + ((size_t)(b * SS) * HH + h) * 16
                        + khalf * 8 + 2 * ku;
    const float4* vbase = (const float4*)v + ((size_t)(b * SS + vo * 8) * HH + h) * 16
                        + vvc;

    // Q B-frags: q = sub*16+n16, d = ks*32+quad*8+j, pre-scaled 1/8
    bf16x8 qf[2][2];
    #pragma unroll
    for (int s = 0; s < 2; ++s)
      #pragma unroll
      for (int ks = 0; ks < 2; ++ks) {
        const float* p = q + (((size_t)(b * SS + qbase + s * 16 + n16) * HH + h) * DD)
                           + ks * 32 + quad * 8;
        float4 x = ((const float4*)p)[0];
        float4 y = ((const float4*)p)[1];
        bf16x8 f;
        f[0] = (short)f2bf(x.x * 0.125f); f[1] = (short)f2bf(x.y * 0.125f);
        f[2] = (short)f2bf(x.z * 0.125f); f[3] = (short)f2bf(x.w * 0.125f);
        f[4] = (short)f2bf(y.x * 0.125f); f[5] = (short)f2bf(y.y * 0.125f);
        f[6] = (short)f2bf(y.z * 0.125f); f[7] = (short)f2bf(y.w * 0.125f);
        qf[s][ks] = f;
      }

    f32x4 oacc[2][4];    // O^T: row d = dt*16+quad*4+r, col q = sub*16+n16
    #pragma unroll
    for (int s = 0; s < 2; ++s)
      #pragma unroll
      for (int dt = 0; dt < 4; ++dt) oacc[s][dt] = f32x4{0.f, 0.f, 0.f, 0.f};
    float su[2] = {0.f, 0.f};

    // per-lane swizzled read offsets inside a slot (r9/r10-identical)
    const unsigned okK = swz1k(((unsigned)n16 << 6) | ((unsigned)quad << 4));
    const unsigned okV = swz1k(((unsigned)quad << 8) | ((unsigned)n16 << 4));

#define ISSUE(ci, kr, vr) do {                                                   \
    const int c_ = cbase + (ci);                                                 \
    const float4* ks_ = kbase + (size_t)(c_ * 32 + ksig) * 256;                  \
    kr[0] = ks_[0]; kr[1] = ks_[1];                                              \
    if (vact) {                                                                  \
        const float4* vs_ = vbase + (size_t)c_ * 8192;                           \
        _Pragma("unroll")                                                        \
        for (int kk_ = 0; kk_ < 8; ++kk_) vr[kk_] = vs_[kk_ * 256];              \
    }                                                                            \
} while (0)

#define WRITE(slot, kr, vr) do {                                                 \
    char* sb_ = (char*)ldsbuf + (slot) * 8192;                                   \
    uint4 kv_;                                                                   \
    kv_.x = pk2(kr[0].x, kr[0].y); kv_.y = pk2(kr[0].z, kr[0].w);                \
    kv_.z = pk2(kr[1].x, kr[1].y); kv_.w = pk2(kr[1].z, kr[1].w);                \
    *(uint4*)(sb_ + kwoff) = kv_;                                                \
    if (vact) {                                                                  \
        const float* fr_ = (const float*)vr;                                     \
        _Pragma("unroll")                                                        \
        for (int cc_ = 0; cc_ < 4; ++cc_) {                                      \
            const int d_ = 4 * vvc + cc_;                                        \
            uint4 q4_;                                                           \
            q4_.x = pk2(fr_[0*4+cc_], fr_[1*4+cc_]);                             \
            q4_.y = pk2(fr_[2*4+cc_], fr_[3*4+cc_]);                             \
            q4_.z = pk2(fr_[4*4+cc_], fr_[5*4+cc_]);                             \
            q4_.w = pk2(fr_[6*4+cc_], fr_[7*4+cc_]);                             \
            *(uint4*)(sb_ + 4096 + (d_ >> 4) * 1024 +                            \
                      swz1k((unsigned)(vo * 256 + (d_ & 15) * 16))) = q4_;       \
        }                                                                        \
    }                                                                            \
} while (0)

// raw barrier: drain LDS writes, NEVER vmcnt (keeps global prefetch in flight)
#define BAR asm volatile("s_waitcnt lgkmcnt(0)\n\ts_barrier" ::: "memory")

#define COMPUTE(slot) do {                                                       \
    const char* cb_ = (const char*)ldsbuf + (slot) * 8192;                       \
    bf16x8 K0 = *(const bf16x8*)(cb_ + okK);                                     \
    bf16x8 K1 = *(const bf16x8*)(cb_ + okK + 1024);                              \
    bf16x8 K2 = *(const bf16x8*)(cb_ + okK + 2048);                              \
    bf16x8 K3 = *(const bf16x8*)(cb_ + okK + 3072);                              \
    bf16x8 V0 = *(const bf16x8*)(cb_ + okV + 4096);                              \
    bf16x8 V1 = *(const bf16x8*)(cb_ + okV + 5120);                              \
    bf16x8 V2 = *(const bf16x8*)(cb_ + okV + 6144);                              \
    bf16x8 V3 = *(const bf16x8*)(cb_ + okV + 7168);                              \
    step32v(K0, K1, K2, K3, V0, V1, V2, V3, qf, oacc, su);                       \
} while (0)

    float4 krA[2], vrA[8], krB[2], vrB[8];

    // prologue: chunks 0,1 in flight
    ISSUE(0, krA, vrA);
    ISSUE(1, krB, vrB);

    // superstep: write 2 chunks, prefetch 2, ONE barrier, compute 2 (ILP x2)
    #pragma unroll 1
    for (int j = 0; j < 8; ++j) {
        const int i = j * 2;
        WRITE(i & 3, krA, vrA);                            // vmcnt auto-wait
        WRITE((i + 1) & 3, krB, vrB);
        { const int ci = (i + 2 < 16) ? i + 2 : 15; ISSUE(ci, krA, vrA); }
        { const int ci = (i + 3 < 16) ? i + 3 : 15; ISSUE(ci, krB, vrB); }
        BAR;
        COMPUTE(i & 3);
        COMPUTE((i + 1) & 3);
    }
#undef ISSUE
#undef WRITE
#undef BAR
#undef COMPUTE

    // epilogue: reduce su across quads, store RAW partials (no normalize)
    #pragma unroll
    for (int s = 0; s < 2; ++s) {
        su[s] += __shfl_xor(su[s], 16);
        su[s] += __shfl_xor(su[s], 32);
    }
    const int pb = bh * 8 + qt;                       // 0..511
    float4* wo4 = (float4*)wso + (size_t)half * 1048576u;
    #pragma unroll
    for (int s = 0; s < 2; ++s)
      #pragma unroll
      for (int dt = 0; dt < 4; ++dt) {
        float4 val;
        val.x = oacc[s][dt][0]; val.y = oacc[s][dt][1];
        val.z = oacc[s][dt][2]; val.w = oacc[s][dt][3];
        wo4[((size_t)pb * 128 + w * 32 + s * 16 + n16) * 16 + dt * 4 + quad] = val;
      }
    if (quad == 0) {
        wss[half * 65536 + pb * 128 + w * 32 + n16]      = su[0];
        wss[half * 65536 + pb * 128 + w * 32 + 16 + n16] = su[1];
    }
}

// ---------------- combine: out = (oA+oB) / (suA+suB) ----------------
__global__ __launch_bounds__(256)
void combine_kernel(const float* __restrict__ wso, const float* __restrict__ wss,
                    float* __restrict__ out) {
    const unsigned gi = blockIdx.x * 256u + threadIdx.x;   // 0..1048575 float4s
    const unsigned row = gi >> 4, d4 = gi & 15;            // row 0..65535
    const float4* o4 = (const float4*)wso;
    float4 a = o4[gi];
    float4 c = o4[gi + 1048576u];
    float sc = 1.0f / (wss[row] + wss[row + 65536]);       // clamps inactive
    const unsigned pb = row >> 7, r128 = row & 127;
    const unsigned bh = pb >> 3, qt = pb & 7;
    const unsigned b = bh >> 4, h = bh & 15;
    float4 val;
    val.x = (a.x + c.x) * sc; val.y = (a.y + c.y) * sc;
    val.z = (a.z + c.z) * sc; val.w = (a.w + c.w) * sc;
    ((float4*)out)[(((size_t)b * SS + qt * 128 + r128) * HH + h) * 16 + d4] = val;
}

extern "C" void kernel_launch(void* const* d_in, const int* in_sizes, int n_in,
                              void* d_out, int out_size, void* d_ws, size_t ws_size,
                              hipStream_t stream) {
    const float* q = (const float*)d_in[0];
    const float* k = (const float*)d_in[1];
    const float* v = (const float*)d_in[2];
    float* o = (float*)d_out;
    float* wso = (float*)d_ws;                 // 2 x 65536 rows x 64 d = 32 MB
    float* wss = wso + 8388608;                // 2 x 65536 su = 0.5 MB
    hipLaunchKernelGGL(attn_partial, dim3(1024), dim3(256), 0, stream, q, k, v, wso, wss);
    hipLaunchKernelGGL(combine_kernel, dim3(4096), dim3(256), 0, stream, wso, wss, o);
}

// Round 8
// 119.272 us; speedup vs baseline: 2.1618x; 1.1467x over previous
//
#include <hip/hip_runtime.h>

// B=4, S=1024, H=16, D=64 attention, clipped softmax.
// Round 16: FUSED + SUPERSTEP (merge of the two proven winners).
//  - r15 proved superstep ILP (2 chunks per barrier, A/B staging sets):
//    attn 66 -> 56us. But split-K's combine + 64MB partial traffic cost
//    ~15us -> total LOSS vs fused r10 (137 vs 123.7).
//  - This round: r10's fused single kernel (512 blocks, direct normalized
//    output, no workspace) with r15's superstep schedule, + s_setprio(1)
//    around the compute pair (T5: blocks are barrier-independent; m191's
//    attn case). All staging/packing/compute bytes r10/r15-verbatim.
// Stall math (r15 counters): 2100 cyc/wave-step vs ~410 VALU-issue cyc ->
// still 2.5x above the VALU-issue bound; barrier amortization + priority
// arbitration is the axis, not memory volume.
// LDS image per 32-key chunk slot (r9/r10-proven):
//   K: [frag 0..3][swz1k(n16*64 + quad*16)]       (4 x 1KB)
//   V: 4096 + [dt 0..3][swz1k(o*256 + n16v*16)]   (4 x 1KB)
#define SS 1024
#define HH 16
#define DD 64

typedef short bf16x8 __attribute__((ext_vector_type(8)));
typedef float f32x4 __attribute__((ext_vector_type(4)));

__device__ __forceinline__ unsigned pk2(float a, float b) {   // pack 2 bf16
    unsigned ua = __float_as_uint(a) + 0x8000u;
    unsigned ub = __float_as_uint(b) + 0x8000u;
    return (ub & 0xffff0000u) | (ua >> 16);
}
__device__ __forceinline__ unsigned short f2bf(float a) {
    return (unsigned short)((__float_as_uint(a) + 0x8000u) >> 16);
}
__device__ __forceinline__ f32x4 mfma16(bf16x8 a, bf16x8 b, f32x4 c) {
    return __builtin_amdgcn_mfma_f32_16x16x32_bf16(a, b, c, 0, 0, 0);
}
// sigma within 32-key chunks (verified r4/r5): pos x holds key ((q^(b>>1))<<3)|(a<<2)|b
__device__ __forceinline__ int sig5(int x) {
    int a = (x >> 4) & 1, qs = (x >> 2) & 3, b2 = x & 3;
    return ((qs ^ (b2 >> 1)) << 3) | (a << 2) | b2;
}
// bank-conflict swizzle within a 1KB fragment (r9-proven): XOR bits 7..9 into 4..6
__device__ __forceinline__ unsigned swz1k(unsigned o) {
    return o ^ (((o >> 7) & 7u) << 4);
}

// compute one 32-key step: QK^T -> exp -> PV (all in registers) [r8..r15-proven]
__device__ __forceinline__ void step32v(bf16x8 K0, bf16x8 K1, bf16x8 K2, bf16x8 K3,
                                        bf16x8 V0, bf16x8 V1, bf16x8 V2, bf16x8 V3,
                                        const bf16x8 qf[2][2],
                                        f32x4 oacc[2][4], float su[2]) {
    const f32x4 zero = {0.f, 0.f, 0.f, 0.f};
    const float LOG2E = 1.44269504f;
    f32x4 S[2][2];
    S[0][0] = mfma16(K1, qf[0][1], mfma16(K0, qf[0][0], zero));
    S[1][0] = mfma16(K1, qf[1][1], mfma16(K0, qf[1][0], zero));
    S[0][1] = mfma16(K3, qf[0][1], mfma16(K2, qf[0][0], zero));
    S[1][1] = mfma16(K3, qf[1][1], mfma16(K2, qf[1][0], zero));
    #pragma unroll
    for (int s = 0; s < 2; ++s) {
        unsigned P0[2], P1[2];
        #pragma unroll
        for (int ct = 0; ct < 2; ++ct) {
            float e0 = __builtin_amdgcn_exp2f(S[s][ct][0] * LOG2E);
            float e1 = __builtin_amdgcn_exp2f(S[s][ct][1] * LOG2E);
            float e2 = __builtin_amdgcn_exp2f(S[s][ct][2] * LOG2E);
            float e3 = __builtin_amdgcn_exp2f(S[s][ct][3] * LOG2E);
            su[s] += (e0 + e1) + (e2 + e3);
            P0[ct] = pk2(e0, e1);
            P1[ct] = pk2(e2, e3);
        }
        union { uint4 u; bf16x8 f; } pf;
        pf.u.x = P0[0];
        pf.u.y = (unsigned)__shfl_xor((int)P1[0], 16);
        pf.u.z = P0[1];
        pf.u.w = (unsigned)__shfl_xor((int)P1[1], 16);
        #pragma unroll
        for (int dt = 0; dt < 4; ++dt) {
            bf16x8 vv = dt == 0 ? V0 : dt == 1 ? V1 : dt == 2 ? V2 : V3;
            oacc[s][dt] = mfma16(vv, pf.f, oacc[s][dt]);
        }
    }
}

// ---------------- fused streaming attention, superstep schedule ----------------
__global__ __launch_bounds__(256, 2)
void attn_fused(const float* __restrict__ q, const float* __restrict__ k,
                const float* __restrict__ v, float* __restrict__ out) {
    // 4-slot ring, 8KB/slot: [0,4K) = K frags (4x1KB), [4K,8K) = V frags
    __shared__ __align__(16) unsigned short ldsbuf[16384];   // 32 KB

    const int t = threadIdx.x, lane = t & 63, w = t >> 6;
    const int n16 = lane & 15, quad = lane >> 4;
    const int bx = blockIdx.x;               // 512 blocks
    const int bh = bx & 63, qt = bx >> 6;    // XCD swizzle: same bh -> same bx%8
    const int h = bh & 15, b = bh >> 4;
    const int qbase = qt * 128 + w * 32;

    // ---- staging task decomposition (r10 verbatim) ----
    // K: all 256 threads; thread = (kx 0..31, khalf, ku 0..3), 2 float4 reads,
    //    1 swizzled ds_write_b128
    const int kx = t >> 3, khalf = (t >> 2) & 1, ku = t & 3;
    const int kf = ((kx >> 4) & 1) * 2 + khalf;
    const unsigned kwoff = (unsigned)(kf * 1024)
                         + swz1k((unsigned)((kx & 15) * 64 + ku * 16));
    const int ksig = sig5(kx);
    // V: every 4th thread; vtid = t>>2 = (vo 0..3, vvc 0..15),
    //    8 float4 reads (keys vo*8..+8 at d-group vvc), 4 swizzled ds_write_b128
    const bool vact = (t & 3) == 0;
    const int vtid = t >> 2, vo = vtid >> 4, vvc = vtid & 15;

    const float4* kbase = (const float4*)k + ((size_t)(b * SS) * HH + h) * 16
                        + khalf * 8 + 2 * ku;
    const float4* vbase = (const float4*)v + ((size_t)(b * SS + vo * 8) * HH + h) * 16
                        + vvc;

    // Q B-frags: q = sub*16+n16, d = ks*32+quad*8+j, pre-scaled 1/8
    bf16x8 qf[2][2];
    #pragma unroll
    for (int s = 0; s < 2; ++s)
      #pragma unroll
      for (int ks = 0; ks < 2; ++ks) {
        const float* p = q + (((size_t)(b * SS + qbase + s * 16 + n16) * HH + h) * DD)
                           + ks * 32 + quad * 8;
        float4 x = ((const float4*)p)[0];
        float4 y = ((const float4*)p)[1];
        bf16x8 f;
        f[0] = (short)f2bf(x.x * 0.125f); f[1] = (short)f2bf(x.y * 0.125f);
        f[2] = (short)f2bf(x.z * 0.125f); f[3] = (short)f2bf(x.w * 0.125f);
        f[4] = (short)f2bf(y.x * 0.125f); f[5] = (short)f2bf(y.y * 0.125f);
        f[6] = (short)f2bf(y.z * 0.125f); f[7] = (short)f2bf(y.w * 0.125f);
        qf[s][ks] = f;
      }

    f32x4 oacc[2][4];    // O^T: row d = dt*16+quad*4+r, col q = sub*16+n16
    #pragma unroll
    for (int s = 0; s < 2; ++s)
      #pragma unroll
      for (int dt = 0; dt < 4; ++dt) oacc[s][dt] = f32x4{0.f, 0.f, 0.f, 0.f};
    float su[2] = {0.f, 0.f};

    // per-lane swizzled read offsets inside a slot (r9/r10-identical)
    const unsigned okK = swz1k(((unsigned)n16 << 6) | ((unsigned)quad << 4));
    const unsigned okV = swz1k(((unsigned)quad << 8) | ((unsigned)n16 << 4));

#define ISSUE(ci, kr, vr) do {                                                   \
    const int c_ = (ci);                                                         \
    const float4* ks_ = kbase + (size_t)(c_ * 32 + ksig) * 256;                  \
    kr[0] = ks_[0]; kr[1] = ks_[1];                                              \
    if (vact) {                                                                  \
        const float4* vs_ = vbase + (size_t)c_ * 8192;                           \
        _Pragma("unroll")                                                        \
        for (int kk_ = 0; kk_ < 8; ++kk_) vr[kk_] = vs_[kk_ * 256];              \
    }                                                                            \
} while (0)

#define WRITE(slot, kr, vr) do {                                                 \
    char* sb_ = (char*)ldsbuf + (slot) * 8192;                                   \
    uint4 kv_;                                                                   \
    kv_.x = pk2(kr[0].x, kr[0].y); kv_.y = pk2(kr[0].z, kr[0].w);                \
    kv_.z = pk2(kr[1].x, kr[1].y); kv_.w = pk2(kr[1].z, kr[1].w);                \
    *(uint4*)(sb_ + kwoff) = kv_;                                                \
    if (vact) {                                                                  \
        const float* fr_ = (const float*)vr;                                     \
        _Pragma("unroll")                                                        \
        for (int cc_ = 0; cc_ < 4; ++cc_) {                                      \
            const int d_ = 4 * vvc + cc_;                                        \
            uint4 q4_;                                                           \
            q4_.x = pk2(fr_[0*4+cc_], fr_[1*4+cc_]);                             \
            q4_.y = pk2(fr_[2*4+cc_], fr_[3*4+cc_]);                             \
            q4_.z = pk2(fr_[4*4+cc_], fr_[5*4+cc_]);                             \
            q4_.w = pk2(fr_[6*4+cc_], fr_[7*4+cc_]);                             \
            *(uint4*)(sb_ + 4096 + (d_ >> 4) * 1024 +                            \
                      swz1k((unsigned)(vo * 256 + (d_ & 15) * 16))) = q4_;       \
        }                                                                        \
    }                                                                            \
} while (0)

// raw barrier: drain LDS writes, NEVER vmcnt (keeps global prefetch in flight)
#define BAR asm volatile("s_waitcnt lgkmcnt(0)\n\ts_barrier" ::: "memory")

#define COMPUTE(slot) do {                                                       \
    const char* cb_ = (const char*)ldsbuf + (slot) * 8192;                       \
    bf16x8 K0 = *(const bf16x8*)(cb_ + okK);                                     \
    bf16x8 K1 = *(const bf16x8*)(cb_ + okK + 1024);                              \
    bf16x8 K2 = *(const bf16x8*)(cb_ + okK + 2048);                              \
    bf16x8 K3 = *(const bf16x8*)(cb_ + okK + 3072);                              \
    bf16x8 V0 = *(const bf16x8*)(cb_ + okV + 4096);                              \
    bf16x8 V1 = *(const bf16x8*)(cb_ + okV + 5120);                              \
    bf16x8 V2 = *(const bf16x8*)(cb_ + okV + 6144);                              \
    bf16x8 V3 = *(const bf16x8*)(cb_ + okV + 7168);                              \
    step32v(K0, K1, K2, K3, V0, V1, V2, V3, qf, oacc, su);                       \
} while (0)

    float4 krA[2], vrA[8], krB[2], vrB[8];

    // prologue: chunks 0,1 in flight
    ISSUE(0, krA, vrA);
    ISSUE(1, krB, vrB);

    // superstep: write 2 chunks, prefetch 2, ONE barrier, compute 2 (ILP x2).
    // setprio(1) around the compute pair: favors compute-phase waves over
    // co-resident staging-phase waves (blocks are barrier-independent).
    #pragma unroll 1
    for (int j = 0; j < 16; ++j) {
        const int i = j * 2;
        WRITE(i & 3, krA, vrA);                            // vmcnt auto-wait
        WRITE((i + 1) & 3, krB, vrB);
        { const int ci = (i + 2 < 32) ? i + 2 : 31; ISSUE(ci, krA, vrA); }
        { const int ci = (i + 3 < 32) ? i + 3 : 31; ISSUE(ci, krB, vrB); }
        BAR;
        __builtin_amdgcn_s_setprio(1);
        COMPUTE(i & 3);
        COMPUTE((i + 1) & 3);
        __builtin_amdgcn_s_setprio(0);
    }
#undef ISSUE
#undef WRITE
#undef BAR
#undef COMPUTE

    // epilogue: reduce su across quads (q lives on n16), normalize, store
    #pragma unroll
    for (int s = 0; s < 2; ++s) {
        su[s] += __shfl_xor(su[s], 16);
        su[s] += __shfl_xor(su[s], 32);
    }
    #pragma unroll
    for (int s = 0; s < 2; ++s) {
        float sc = 1.0f / su[s];     // clamps proven inactive; e^{-C'} cancels
        #pragma unroll
        for (int dt = 0; dt < 4; ++dt) {
            float4 val;
            val.x = oacc[s][dt][0] * sc;
            val.y = oacc[s][dt][1] * sc;
            val.z = oacc[s][dt][2] * sc;
            val.w = oacc[s][dt][3] * sc;
            size_t off = ((size_t)(b * SS + qbase + s * 16 + n16) * HH + h) * DD
                       + dt * 16 + quad * 4;
            *(float4*)&out[off] = val;
        }
    }
}

extern "C" void kernel_launch(void* const* d_in, const int* in_sizes, int n_in,
                              void* d_out, int out_size, void* d_ws, size_t ws_size,
                              hipStream_t stream) {
    const float* q = (const float*)d_in[0];
    const float* k = (const float*)d_in[1];
    const float* v = (const float*)d_in[2];
    float* o = (float*)d_out;
    (void)d_ws; (void)ws_size;   // workspace unused: no partials, no combine
    hipLaunchKernelGGL(attn_fused, dim3(512), dim3(256), 0, stream, q, k, v, o);
}

// Round 10
// 110.813 us; speedup vs baseline: 2.3268x; 1.0763x over previous
//
#include <hip/hip_runtime.h>

// B=4, S=1024, H=16, D=64 attention, clipped softmax.
// Round 18: full-wave V staging (r11's redistribution + proven pk2) on r16.
// DIAGNOSIS from r17 fail (absmax 0.257 ~= r11's 0.27): the shared ingredient
// across both failures is the inline-asm v_cvt_pk_bf16_f32; all 5 passing
// rounds use pk2. r11's V-redistribution re-audited byte-for-byte vs the r10
// image (dt=vg>>2, n16v=4(vg&3)+c, o2=w, +vp*4 commutes with swz1k, lo=even
// key) -> it is correct; cvtpk was the bug. cvtpk BANNED; redist re-enters
// with pk2 as the single delta on r16 (PASSED, 119.3us, attn 52).
// Why: V-pack 16 quarter-active pk2 (48 wave-issue instrs/chunk) -> 4
// full-wave pk2 (12 instrs); V staging regs 8->2 float4 per set (-48 VGPR);
// V loads 8 quarter-wave -> 2 full-wave instrs. LDS image bytes UNCHANGED.
// LDS image per 32-key chunk slot (r9/r10-proven):
//   K: [frag 0..3][swz1k(n16*64 + quad*16)]       (4 x 1KB)
//   V: 4096 + [dt 0..3][swz1k(o2*256 + n16v*16)]  (4 x 1KB)
#define SS 1024
#define HH 16
#define DD 64

typedef short bf16x8 __attribute__((ext_vector_type(8)));
typedef float f32x4 __attribute__((ext_vector_type(4)));

__device__ __forceinline__ unsigned pk2(float a, float b) {   // pack 2 bf16
    unsigned ua = __float_as_uint(a) + 0x8000u;
    unsigned ub = __float_as_uint(b) + 0x8000u;
    return (ub & 0xffff0000u) | (ua >> 16);
}
__device__ __forceinline__ unsigned short f2bf(float a) {
    return (unsigned short)((__float_as_uint(a) + 0x8000u) >> 16);
}
__device__ __forceinline__ f32x4 mfma16(bf16x8 a, bf16x8 b, f32x4 c) {
    return __builtin_amdgcn_mfma_f32_16x16x32_bf16(a, b, c, 0, 0, 0);
}
// sigma within 32-key chunks (verified r4/r5): pos x holds key ((q^(b>>1))<<3)|(a<<2)|b
__device__ __forceinline__ int sig5(int x) {
    int a = (x >> 4) & 1, qs = (x >> 2) & 3, b2 = x & 3;
    return ((qs ^ (b2 >> 1)) << 3) | (a << 2) | b2;
}
// bank-conflict swizzle within a 1KB fragment (r9-proven): XOR bits 7..9 into 4..6
__device__ __forceinline__ unsigned swz1k(unsigned o) {
    return o ^ (((o >> 7) & 7u) << 4);
}

// compute one 32-key step: QK^T -> exp -> PV (all in registers) [r8..r16-proven]
__device__ __forceinline__ void step32v(bf16x8 K0, bf16x8 K1, bf16x8 K2, bf16x8 K3,
                                        bf16x8 V0, bf16x8 V1, bf16x8 V2, bf16x8 V3,
                                        const bf16x8 qf[2][2],
                                        f32x4 oacc[2][4], float su[2]) {
    const f32x4 zero = {0.f, 0.f, 0.f, 0.f};
    const float LOG2E = 1.44269504f;
    f32x4 S[2][2];
    S[0][0] = mfma16(K1, qf[0][1], mfma16(K0, qf[0][0], zero));
    S[1][0] = mfma16(K1, qf[1][1], mfma16(K0, qf[1][0], zero));
    S[0][1] = mfma16(K3, qf[0][1], mfma16(K2, qf[0][0], zero));
    S[1][1] = mfma16(K3, qf[1][1], mfma16(K2, qf[1][0], zero));
    #pragma unroll
    for (int s = 0; s < 2; ++s) {
        unsigned P0[2], P1[2];
        #pragma unroll
        for (int ct = 0; ct < 2; ++ct) {
            float e0 = __builtin_amdgcn_exp2f(S[s][ct][0] * LOG2E);
            float e1 = __builtin_amdgcn_exp2f(S[s][ct][1] * LOG2E);
            float e2 = __builtin_amdgcn_exp2f(S[s][ct][2] * LOG2E);
            float e3 = __builtin_amdgcn_exp2f(S[s][ct][3] * LOG2E);
            su[s] += (e0 + e1) + (e2 + e3);
            P0[ct] = pk2(e0, e1);
            P1[ct] = pk2(e2, e3);
        }
        union { uint4 u; bf16x8 f; } pf;
        pf.u.x = P0[0];
        pf.u.y = (unsigned)__shfl_xor((int)P1[0], 16);
        pf.u.z = P0[1];
        pf.u.w = (unsigned)__shfl_xor((int)P1[1], 16);
        #pragma unroll
        for (int dt = 0; dt < 4; ++dt) {
            bf16x8 vv = dt == 0 ? V0 : dt == 1 ? V1 : dt == 2 ? V2 : V3;
            oacc[s][dt] = mfma16(vv, pf.f, oacc[s][dt]);
        }
    }
}

// ---------------- fused streaming attention, superstep schedule ----------------
__global__ __launch_bounds__(256, 2)
void attn_fused(const float* __restrict__ q, const float* __restrict__ k,
                const float* __restrict__ v, float* __restrict__ out) {
    // 4-slot ring, 8KB/slot: [0,4K) = K frags (4x1KB), [4K,8K) = V frags
    __shared__ __align__(16) unsigned short ldsbuf[16384];   // 32 KB

    const int t = threadIdx.x, lane = t & 63, w = t >> 6;
    const int n16 = lane & 15, quad = lane >> 4;
    const int bx = blockIdx.x;               // 512 blocks
    const int bh = bx & 63, qt = bx >> 6;    // XCD swizzle: same bh -> same bx%8
    const int h = bh & 15, b = bh >> 4;
    const int qbase = qt * 128 + w * 32;

    // ---- staging task decomposition ----
    // K (r10/r16 verbatim): thread = (kx 0..31, khalf, ku 0..3), 2 float4 reads,
    //    1 swizzled ds_write_b128
    const int kx = t >> 3, khalf = (t >> 2) & 1, ku = t & 3;
    const int kf = ((kx >> 4) & 1) * 2 + khalf;
    const unsigned kwoff = (unsigned)(kf * 1024)
                         + swz1k((unsigned)((kx & 15) * 64 + ku * 16));
    const int ksig = sig5(kx);
    // V (FULL-WAVE, r11 map re-audited, pk2): thread = (w, vp 0..3, vg 0..15);
    //    loads keys w*8+2vp, +1 at d = 4vg..4vg+3 (2 float4); writes 4 b32
    //    words: pair (key even, key odd) at d = 4vg+c.
    const int vp = (t >> 4) & 3, vg = t & 15;
    unsigned voff[4];
    #pragma unroll
    for (int c = 0; c < 4; ++c)
        voff[c] = 4096u + (unsigned)((vg >> 2) * 1024)
                + swz1k((unsigned)(w * 256 + (4 * (vg & 3) + c) * 16))
                + (unsigned)(vp * 4);

    const float4* kbase = (const float4*)k + ((size_t)(b * SS) * HH + h) * 16
                        + khalf * 8 + 2 * ku;
    const float4* vbase = (const float4*)v
        + ((size_t)(b * SS + w * 8 + 2 * vp) * HH + h) * 16 + vg;

    // Q B-frags: q = sub*16+n16, d = ks*32+quad*8+j, pre-scaled 1/8
    bf16x8 qf[2][2];
    #pragma unroll
    for (int s = 0; s < 2; ++s)
      #pragma unroll
      for (int ks = 0; ks < 2; ++ks) {
        const float* p = q + (((size_t)(b * SS + qbase + s * 16 + n16) * HH + h) * DD)
                           + ks * 32 + quad * 8;
        float4 x = ((const float4*)p)[0];
        float4 y = ((const float4*)p)[1];
        bf16x8 f;
        f[0] = (short)f2bf(x.x * 0.125f); f[1] = (short)f2bf(x.y * 0.125f);
        f[2] = (short)f2bf(x.z * 0.125f); f[3] = (short)f2bf(x.w * 0.125f);
        f[4] = (short)f2bf(y.x * 0.125f); f[5] = (short)f2bf(y.y * 0.125f);
        f[6] = (short)f2bf(y.z * 0.125f); f[7] = (short)f2bf(y.w * 0.125f);
        qf[s][ks] = f;
      }

    f32x4 oacc[2][4];    // O^T: row d = dt*16+quad*4+r, col q = sub*16+n16
    #pragma unroll
    for (int s = 0; s < 2; ++s)
      #pragma unroll
      for (int dt = 0; dt < 4; ++dt) oacc[s][dt] = f32x4{0.f, 0.f, 0.f, 0.f};
    float su[2] = {0.f, 0.f};

    // per-lane swizzled read offsets inside a slot (r9/r10-identical)
    const unsigned okK = swz1k(((unsigned)n16 << 6) | ((unsigned)quad << 4));
    const unsigned okV = swz1k(((unsigned)quad << 8) | ((unsigned)n16 << 4));

#define ISSUE(ci, kr, vr) do {                                                   \
    const int c_ = (ci);                                                         \
    const float4* ks_ = kbase + (size_t)(c_ * 32 + ksig) * 256;                  \
    kr[0] = ks_[0]; kr[1] = ks_[1];                                              \
    const float4* vs_ = vbase + (size_t)c_ * 8192;                               \
    vr[0] = vs_[0]; vr[1] = vs_[256];                                            \
} while (0)

#define WRITE(slot, kr, vr) do {                                                 \
    char* sb_ = (char*)ldsbuf + (slot) * 8192;                                   \
    uint4 kv_;                                                                   \
    kv_.x = pk2(kr[0].x, kr[0].y); kv_.y = pk2(kr[0].z, kr[0].w);                \
    kv_.z = pk2(kr[1].x, kr[1].y); kv_.w = pk2(kr[1].z, kr[1].w);                \
    *(uint4*)(sb_ + kwoff) = kv_;                                                \
    *(unsigned*)(sb_ + voff[0]) = pk2(vr[0].x, vr[1].x);                         \
    *(unsigned*)(sb_ + voff[1]) = pk2(vr[0].y, vr[1].y);                         \
    *(unsigned*)(sb_ + voff[2]) = pk2(vr[0].z, vr[1].z);                         \
    *(unsigned*)(sb_ + voff[3]) = pk2(vr[0].w, vr[1].w);                         \
} while (0)

// raw barrier: drain LDS writes, NEVER vmcnt (keeps global prefetch in flight)
#define BAR asm volatile("s_waitcnt lgkmcnt(0)\n\ts_barrier" ::: "memory")

#define COMPUTE(slot) do {                                                       \
    const char* cb_ = (const char*)ldsbuf + (slot) * 8192;                       \
    bf16x8 K0 = *(const bf16x8*)(cb_ + okK);                                     \
    bf16x8 K1 = *(const bf16x8*)(cb_ + okK + 1024);                              \
    bf16x8 K2 = *(const bf16x8*)(cb_ + okK + 2048);                              \
    bf16x8 K3 = *(const bf16x8*)(cb_ + okK + 3072);                              \
    bf16x8 V0 = *(const bf16x8*)(cb_ + okV + 4096);                              \
    bf16x8 V1 = *(const bf16x8*)(cb_ + okV + 5120);                              \
    bf16x8 V2 = *(const bf16x8*)(cb_ + okV + 6144);                              \
    bf16x8 V3 = *(const bf16x8*)(cb_ + okV + 7168);                              \
    step32v(K0, K1, K2, K3, V0, V1, V2, V3, qf, oacc, su);                       \
} while (0)

    float4 krA[2], vrA[2], krB[2], vrB[2];

    // prologue: chunks 0,1 in flight
    ISSUE(0, krA, vrA);
    ISSUE(1, krB, vrB);

    // superstep: write 2 chunks, prefetch 2, ONE barrier, compute 2 (ILP x2).
    // setprio(1) around the compute pair (r16-proven schedule).
    #pragma unroll 1
    for (int j = 0; j < 16; ++j) {
        const int i = j * 2;
        WRITE(i & 3, krA, vrA);                            // vmcnt auto-wait
        WRITE((i + 1) & 3, krB, vrB);
        { const int ci = (i + 2 < 32) ? i + 2 : 31; ISSUE(ci, krA, vrA); }
        { const int ci = (i + 3 < 32) ? i + 3 : 31; ISSUE(ci, krB, vrB); }
        BAR;
        __builtin_amdgcn_s_setprio(1);
        COMPUTE(i & 3);
        COMPUTE((i + 1) & 3);
        __builtin_amdgcn_s_setprio(0);
    }
#undef ISSUE
#undef WRITE
#undef BAR
#undef COMPUTE

    // epilogue: reduce su across quads (q lives on n16), normalize, store
    #pragma unroll
    for (int s = 0; s < 2; ++s) {
        su[s] += __shfl_xor(su[s], 16);
        su[s] += __shfl_xor(su[s], 32);
    }
    #pragma unroll
    for (int s = 0; s < 2; ++s) {
        float sc = 1.0f / su[s];     // clamps proven inactive; e^{-C'} cancels
        #pragma unroll
        for (int dt = 0; dt < 4; ++dt) {
            float4 val;
            val.x = oacc[s][dt][0] * sc;
            val.y = oacc[s][dt][1] * sc;
            val.z = oacc[s][dt][2] * sc;
            val.w = oacc[s][dt][3] * sc;
            size_t off = ((size_t)(b * SS + qbase + s * 16 + n16) * HH + h) * DD
                       + dt * 16 + quad * 4;
            *(float4*)&out[off] = val;
        }
    }
}

extern "C" void kernel_launch(void* const* d_in, const int* in_sizes, int n_in,
                              void* d_out, int out_size, void* d_ws, size_t ws_size,
                              hipStream_t stream) {
    const float* q = (const float*)d_in[0];
    const float* k = (const float*)d_in[1];
    const float* v = (const float*)d_in[2];
    float* o = (float*)d_out;
    (void)d_ws; (void)ws_size;   // workspace unused
    hipLaunchKernelGGL(attn_fused, dim3(512), dim3(256), 0, stream, q, k, v, o);
}